// Round 5
// baseline (227.855 us; speedup 1.0000x reference)
//
#include <hip/hip_runtime.h>
#include <hip/hip_bf16.h>
#include <math.h>

#define D_DIM 2048
#define L_DIM 64
#define E_NUM 64
#define H_DIM 64

typedef float f32x4_t __attribute__((ext_vector_type(4)));
typedef __bf16 bf16x8_t __attribute__((ext_vector_type(8)));

// ---------------- workspace layout (bytes) ----------------
// upart [64][2048] f32 (512 KB) | sel[2] int | g[2] float
#define WS_UPART 0u
#define WS_SEL   (64u * 2048u * 4u)
#define WS_G     (WS_SEL + 8u)

// ------- kernel 1: upart[c][d] = sum_{s in 128-row chunk c} x[s,d]*wout[s] ----
// (byte-identical to the round-3 version that passed all checks)
__global__ __launch_bounds__(256) void k_upart(const float* __restrict__ x,
                                               const float* __restrict__ wout,
                                               float* __restrict__ upart) {
  const int d4 = (blockIdx.x * 256 + threadIdx.x) * 4;  // gridDim.x == 2
  const int s0 = blockIdx.y * 128;                      // gridDim.y == 64
  const float* xp = x + (size_t)s0 * D_DIM + d4;
  float4 acc0 = make_float4(0.f, 0.f, 0.f, 0.f);
  float4 acc1 = make_float4(0.f, 0.f, 0.f, 0.f);
#pragma unroll 8
  for (int i = 0; i < 128; i += 2) {
    const float w0 = wout[s0 + i];
    const float w1 = wout[s0 + i + 1];
    const float4 a = *reinterpret_cast<const float4*>(xp + (size_t)i * D_DIM);
    const float4 b = *reinterpret_cast<const float4*>(xp + (size_t)(i + 1) * D_DIM);
    acc0.x += a.x * w0; acc0.y += a.y * w0; acc0.z += a.z * w0; acc0.w += a.w * w0;
    acc1.x += b.x * w1; acc1.y += b.y * w1; acc1.z += b.z * w1; acc1.w += b.w * w1;
  }
  acc0.x += acc1.x; acc0.y += acc1.y; acc0.z += acc1.z; acc0.w += acc1.w;
  *reinterpret_cast<float4*>(upart + (size_t)blockIdx.y * D_DIM + d4) = acc0;
}

// ------- kernel 2: fused u-reduce + v = Wg_in u + scores + top2 + softmax ----
// (byte-identical to the round-3 version that passed all checks)
__global__ __launch_bounds__(1024) void k_gate_all(
    const float* __restrict__ upart, const float* __restrict__ wg_in,
    const float* __restrict__ wg_lin, int* __restrict__ sel, float* __restrict__ g) {
  __shared__ float uS[D_DIM];
  __shared__ float vS[H_DIM];
  __shared__ float scS[E_NUM];
  const int t = threadIdx.x;
  for (int dd = t; dd < D_DIM; dd += 1024) {
    float s = 0.f;
#pragma unroll 8
    for (int c = 0; c < 64; ++c) s += upart[(size_t)c * D_DIM + dd];
    uS[dd] = s;
  }
  __syncthreads();
  const int w = t >> 6, lane = t & 63;
  for (int hh = w; hh < H_DIM; hh += 16) {
    const float4* wr = reinterpret_cast<const float4*>(wg_in + (size_t)hh * D_DIM);
    float s = 0.f;
#pragma unroll
    for (int j = 0; j < 8; ++j) {
      const float4 a = wr[lane + 64 * j];
      const float* ub = &uS[(lane + 64 * j) * 4];
      s += a.x * ub[0] + a.y * ub[1] + a.z * ub[2] + a.w * ub[3];
    }
#pragma unroll
    for (int off = 32; off; off >>= 1) s += __shfl_down(s, off, 64);
    if (lane == 0) vS[hh] = s;
  }
  __syncthreads();
  if (t < E_NUM) {
    float s = 0.f;
#pragma unroll 8
    for (int hh = 0; hh < H_DIM; ++hh) s += wg_lin[t * H_DIM + hh] * vS[hh];
    scS[t] = s;
  }
  __syncthreads();
  if (t == 0) {
    int b1 = 0; float m1 = scS[0];
    for (int e = 1; e < E_NUM; ++e) { if (scS[e] > m1) { m1 = scS[e]; b1 = e; } }
    int b2 = -1; float m2 = -3.4e38f;
    for (int e = 0; e < E_NUM; ++e) { if (e != b1 && scS[e] > m2) { m2 = scS[e]; b2 = e; } }
    const float e2 = expf(m2 - m1);
    const float g0 = 1.0f / (1.0f + e2);
    sel[0] = b1; sel[1] = b2;
    g[0] = g0; g[1] = 1.0f - g0;
  }
}

// ---------------- kernel 3: barrier-free direct-global MFMA GEMM ----------
// Reads We (fp32, d_in) directly — no bf16 staging kernel, no ws handoff of
// bulk data. Only sel (8 B) + g (8 B) come from ws.
__device__ __forceinline__ float gelu_f(float v) {
  return 0.5f * v * (1.0f + erff(v * 0.70710678118654752440f));
}

// 256 blocks x 512 threads. Block tile 32(M) x 128(N), K=2048.
// Wave wv: mg=wv>>2 -> 16-row group, ng=wv&3 -> 32-col group.
// Cols 0..63 = expert sel[0], 64..127 = expert sel[1]; col c -> We row l=c&63.
// A-frag: 8 contiguous f32 from x, cvt->bf16 in-reg.
// B-frag: 8 contiguous f32 from We[e,l,:], cvt->bf16 in-reg (L2-resident).
__global__ __launch_bounds__(512) void k_moe_gemm(
    const float* __restrict__ x, const float* __restrict__ we,
    const int* __restrict__ sel, const float* __restrict__ gw,
    float* __restrict__ out) {
  const int tid = threadIdx.x;
  const int wv = tid >> 6, lane = tid & 63;
  const int mg = wv >> 2, ng = wv & 3;
  const int fr = lane & 15, fq = lane >> 4;
  const int mb = blockIdx.x * 32;

  const int e = sel[ng >> 1] & 63;           // clamp: even garbage can't OOB
  const int l0 = (ng & 1) * 32 + fr;

  const float* pa  = x + (size_t)(mb + mg * 16 + fr) * D_DIM + fq * 8;
  const float* pb0 = we + ((size_t)e * L_DIM + l0) * D_DIM + fq * 8;
  const float* pb1 = pb0 + (size_t)16 * D_DIM;

  f32x4_t acc0 = {0.f, 0.f, 0.f, 0.f};
  f32x4_t acc1 = acc0;

#pragma unroll 2
  for (int ks = 0; ks < 64; ++ks) {
    const int k0 = ks * 32;
    const float4 a0 = *reinterpret_cast<const float4*>(pa + k0);
    const float4 a1 = *reinterpret_cast<const float4*>(pa + k0 + 4);
    const float4 b00 = *reinterpret_cast<const float4*>(pb0 + k0);
    const float4 b01 = *reinterpret_cast<const float4*>(pb0 + k0 + 4);
    const float4 b10 = *reinterpret_cast<const float4*>(pb1 + k0);
    const float4 b11 = *reinterpret_cast<const float4*>(pb1 + k0 + 4);
    union { __hip_bfloat16 h[8]; bf16x8_t v; } af, bf0, bf1;
    af.h[0] = __float2bfloat16(a0.x);  af.h[1] = __float2bfloat16(a0.y);
    af.h[2] = __float2bfloat16(a0.z);  af.h[3] = __float2bfloat16(a0.w);
    af.h[4] = __float2bfloat16(a1.x);  af.h[5] = __float2bfloat16(a1.y);
    af.h[6] = __float2bfloat16(a1.z);  af.h[7] = __float2bfloat16(a1.w);
    bf0.h[0] = __float2bfloat16(b00.x); bf0.h[1] = __float2bfloat16(b00.y);
    bf0.h[2] = __float2bfloat16(b00.z); bf0.h[3] = __float2bfloat16(b00.w);
    bf0.h[4] = __float2bfloat16(b01.x); bf0.h[5] = __float2bfloat16(b01.y);
    bf0.h[6] = __float2bfloat16(b01.z); bf0.h[7] = __float2bfloat16(b01.w);
    bf1.h[0] = __float2bfloat16(b10.x); bf1.h[1] = __float2bfloat16(b10.y);
    bf1.h[2] = __float2bfloat16(b10.z); bf1.h[3] = __float2bfloat16(b10.w);
    bf1.h[4] = __float2bfloat16(b11.x); bf1.h[5] = __float2bfloat16(b11.y);
    bf1.h[6] = __float2bfloat16(b11.z); bf1.h[7] = __float2bfloat16(b11.w);
    acc0 = __builtin_amdgcn_mfma_f32_16x16x32_bf16(af.v, bf0.v, acc0, 0, 0, 0);
    acc1 = __builtin_amdgcn_mfma_f32_16x16x32_bf16(af.v, bf1.v, acc1, 0, 0, 0);
  }

  // ---- epilogue: z [32][132] + ps [32][16] in LDS ----
  __shared__ __align__(16) float zs[32 * 132 + 32 * 16];
  float* z = zs;
  float* ps = zs + 32 * 132;
  {
    const int colb = ng * 32 + fr;
    const int rowb = mg * 16 + fq * 4;
#pragma unroll
    for (int reg = 0; reg < 4; ++reg) {
      z[(rowb + reg) * 132 + colb]      = acc0[reg];
      z[(rowb + reg) * 132 + colb + 16] = acc1[reg];
    }
  }
  __syncthreads();
  {
    const int r = tid >> 4, seg = tid & 15;
    float s = 0.f;
#pragma unroll
    for (int i2 = 0; i2 < 8; ++i2) {
      const float t2 = z[r * 132 + seg * 8 + i2];
      s += t2 * t2;
    }
    ps[r * 16 + seg] = s;
  }
  __syncthreads();
  {
    const float g0 = gw[0], g1 = gw[1];
    const int r = tid >> 4, j = tid & 15;
    float s0 = 0.f, s1 = 0.f;
#pragma unroll
    for (int i2 = 0; i2 < 8; ++i2) { s0 += ps[r * 16 + i2]; s1 += ps[r * 16 + 8 + i2]; }
    const float i0 = 1.0f / fmaxf(sqrtf(s0), 1e-12f);
    const float i1 = 1.0f / fmaxf(sqrtf(s1), 1e-12f);
    float o[4];
#pragma unroll
    for (int i2 = 0; i2 < 4; ++i2) {
      const int c = j * 4 + i2;
      o[i2] = g0 * gelu_f(z[r * 132 + c] * i0) + g1 * gelu_f(z[r * 132 + 64 + c] * i1);
    }
    *reinterpret_cast<float4*>(out + (size_t)(mb + r) * 64 + j * 4) =
        make_float4(o[0], o[1], o[2], o[3]);
  }
}

// ---------------- launch ----------------
extern "C" void kernel_launch(void* const* d_in, const int* in_sizes, int n_in,
                              void* d_out, int out_size, void* d_ws, size_t ws_size,
                              hipStream_t stream) {
  (void)in_sizes; (void)n_in; (void)out_size; (void)ws_size;
  const float* x      = (const float*)d_in[0];
  const float* wg_in  = (const float*)d_in[1];
  const float* wg_lin = (const float*)d_in[2];
  const float* wg_out = (const float*)d_in[3];
  const float* we     = (const float*)d_in[4];
  float* out = (float*)d_out;
  char* ws = (char*)d_ws;

  float* upart = (float*)(ws + WS_UPART);
  int*   sel   = (int*)(ws + WS_SEL);
  float* g     = (float*)(ws + WS_G);

  k_upart   <<<dim3(2, 64), 256, 0, stream>>>(x, wg_out, upart);
  k_gate_all<<<1, 1024, 0, stream>>>(upart, wg_in, wg_lin, sel, g);
  k_moe_gemm<<<256, 512, 0, stream>>>(x, we, sel, g, out);
}

// Round 6
// 210.627 us; speedup vs baseline: 1.0818x; 1.0818x over previous
//
#include <hip/hip_runtime.h>
#include <hip/hip_bf16.h>
#include <math.h>

#define D_DIM 2048
#define L_DIM 64
#define E_NUM 64
#define H_DIM 64

typedef float f32x4_t __attribute__((ext_vector_type(4)));
typedef __bf16 bf16x8_t __attribute__((ext_vector_type(8)));

// ---------------- workspace layout (bytes) ----------------
// upart [128][2048] f32 (1 MB) | sel[2] int | g[2] float
#define WS_UPART 0u
#define WS_SEL   (128u * 2048u * 4u)
#define WS_G     (WS_SEL + 8u)

// ------- kernel 1: upart[c][d] = sum_{s in 64-row chunk c} x[s,d]*wout[s] ----
// 256 blocks (dim3(2,128)) so all CUs stream x.
__global__ __launch_bounds__(256) void k_upart(const float* __restrict__ x,
                                               const float* __restrict__ wout,
                                               float* __restrict__ upart) {
  const int d4 = (blockIdx.x * 256 + threadIdx.x) * 4;  // gridDim.x == 2
  const int s0 = blockIdx.y * 64;                        // gridDim.y == 128
  const float* xp = x + (size_t)s0 * D_DIM + d4;
  float4 acc0 = make_float4(0.f, 0.f, 0.f, 0.f);
  float4 acc1 = make_float4(0.f, 0.f, 0.f, 0.f);
#pragma unroll 8
  for (int i = 0; i < 64; i += 2) {
    const float w0 = wout[s0 + i];
    const float w1 = wout[s0 + i + 1];
    const float4 a = *reinterpret_cast<const float4*>(xp + (size_t)i * D_DIM);
    const float4 b = *reinterpret_cast<const float4*>(xp + (size_t)(i + 1) * D_DIM);
    acc0.x += a.x * w0; acc0.y += a.y * w0; acc0.z += a.z * w0; acc0.w += a.w * w0;
    acc1.x += b.x * w1; acc1.y += b.y * w1; acc1.z += b.z * w1; acc1.w += b.w * w1;
  }
  acc0.x += acc1.x; acc0.y += acc1.y; acc0.z += acc1.z; acc0.w += acc1.w;
  *reinterpret_cast<float4*>(upart + (size_t)blockIdx.y * D_DIM + d4) = acc0;
}

// ------- kernel 2: fused u-reduce + v = Wg_in u + scores + top2 + softmax ----
__global__ __launch_bounds__(1024) void k_gate_all(
    const float* __restrict__ upart, const float* __restrict__ wg_in,
    const float* __restrict__ wg_lin, int* __restrict__ sel, float* __restrict__ g) {
  __shared__ float uS[D_DIM];
  __shared__ float vS[H_DIM];
  __shared__ float scS[E_NUM];
  const int t = threadIdx.x;
  for (int dd = t; dd < D_DIM; dd += 1024) {
    float s = 0.f;
#pragma unroll 8
    for (int c = 0; c < 128; ++c) s += upart[(size_t)c * D_DIM + dd];
    uS[dd] = s;
  }
  __syncthreads();
  const int w = t >> 6, lane = t & 63;
  for (int hh = w; hh < H_DIM; hh += 16) {
    const float4* wr = reinterpret_cast<const float4*>(wg_in + (size_t)hh * D_DIM);
    float s = 0.f;
#pragma unroll
    for (int j = 0; j < 8; ++j) {
      const float4 a = wr[lane + 64 * j];
      const float* ub = &uS[(lane + 64 * j) * 4];
      s += a.x * ub[0] + a.y * ub[1] + a.z * ub[2] + a.w * ub[3];
    }
#pragma unroll
    for (int off = 32; off; off >>= 1) s += __shfl_down(s, off, 64);
    if (lane == 0) vS[hh] = s;
  }
  __syncthreads();
  if (t < E_NUM) {
    float s = 0.f;
#pragma unroll 8
    for (int hh = 0; hh < H_DIM; ++hh) s += wg_lin[t * H_DIM + hh] * vS[hh];
    scS[t] = s;
  }
  __syncthreads();
  if (t == 0) {
    int b1 = 0; float m1 = scS[0];
    for (int e = 1; e < E_NUM; ++e) { if (scS[e] > m1) { m1 = scS[e]; b1 = e; } }
    int b2 = -1; float m2 = -3.4e38f;
    for (int e = 0; e < E_NUM; ++e) { if (e != b1 && scS[e] > m2) { m2 = scS[e]; b2 = e; } }
    const float e2 = expf(m2 - m1);
    const float g0 = 1.0f / (1.0f + e2);
    sel[0] = b1; sel[1] = b2;
    g[0] = g0; g[1] = 1.0f - g0;
  }
}

// ---------------- kernel 3: barrier-free direct-global MFMA GEMM ----------
__device__ __forceinline__ float gelu_f(float v) {
  return 0.5f * v * (1.0f + erff(v * 0.70710678118654752440f));
}

__device__ __forceinline__ bf16x8_t cvt8(const float4 a, const float4 b) {
  union { __hip_bfloat16 h[8]; bf16x8_t v; } u;
  u.h[0] = __float2bfloat16(a.x); u.h[1] = __float2bfloat16(a.y);
  u.h[2] = __float2bfloat16(a.z); u.h[3] = __float2bfloat16(a.w);
  u.h[4] = __float2bfloat16(b.x); u.h[5] = __float2bfloat16(b.y);
  u.h[6] = __float2bfloat16(b.z); u.h[7] = __float2bfloat16(b.w);
  return u.v;
}

// 256 blocks x 512 threads. Block tile 32(M) x 128(N), K=2048.
// 8 waves = 4 ng (32-col groups) x 2 kg (K halves of 1024). Wave tile:
// 32 rows x 32 cols, acc[2][2] -> 4 MFMAs per k-step on 8 x 16B loads.
// B-fragment rows are reused across 32 M-rows (2x less L2 B traffic than
// 16-row waves); A is duplicated x4 across ng waves -> L1 serves it.
// kg halves are merged additively in the LDS z-tile (one extra barrier).
__global__ __launch_bounds__(512) void k_moe_gemm(
    const float* __restrict__ x, const float* __restrict__ we,
    const int* __restrict__ sel, const float* __restrict__ gw,
    float* __restrict__ out) {
  const int tid = threadIdx.x;
  const int wv = tid >> 6, lane = tid & 63;
  const int ng = wv & 3, kg = wv >> 2;
  const int fr = lane & 15, fq = lane >> 4;
  const int mb = blockIdx.x * 32;

  const int e = sel[ng >> 1] & 63;           // cols ng*32.. -> expert ng>>1
  const int l0 = (ng & 1) * 32 + fr;         // row within expert: 0..63

  const float* pa0 = x + (size_t)(mb + fr) * D_DIM + kg * 1024 + fq * 8;
  const float* pa1 = pa0 + (size_t)16 * D_DIM;
  const float* pb0 = we + ((size_t)e * L_DIM + l0) * D_DIM + kg * 1024 + fq * 8;
  const float* pb1 = pb0 + (size_t)16 * D_DIM;

  f32x4_t acc00 = {0.f, 0.f, 0.f, 0.f};
  f32x4_t acc01 = acc00, acc10 = acc00, acc11 = acc00;

#pragma unroll 2
  for (int ks = 0; ks < 32; ++ks) {
    const int k0 = ks * 32;
    const float4 a00 = *reinterpret_cast<const float4*>(pa0 + k0);
    const float4 a01 = *reinterpret_cast<const float4*>(pa0 + k0 + 4);
    const float4 a10 = *reinterpret_cast<const float4*>(pa1 + k0);
    const float4 a11 = *reinterpret_cast<const float4*>(pa1 + k0 + 4);
    const float4 b00 = *reinterpret_cast<const float4*>(pb0 + k0);
    const float4 b01 = *reinterpret_cast<const float4*>(pb0 + k0 + 4);
    const float4 b10 = *reinterpret_cast<const float4*>(pb1 + k0);
    const float4 b11 = *reinterpret_cast<const float4*>(pb1 + k0 + 4);
    const bf16x8_t af0 = cvt8(a00, a01);
    const bf16x8_t af1 = cvt8(a10, a11);
    const bf16x8_t bf0 = cvt8(b00, b01);
    const bf16x8_t bf1 = cvt8(b10, b11);
    acc00 = __builtin_amdgcn_mfma_f32_16x16x32_bf16(af0, bf0, acc00, 0, 0, 0);
    acc01 = __builtin_amdgcn_mfma_f32_16x16x32_bf16(af0, bf1, acc01, 0, 0, 0);
    acc10 = __builtin_amdgcn_mfma_f32_16x16x32_bf16(af1, bf0, acc10, 0, 0, 0);
    acc11 = __builtin_amdgcn_mfma_f32_16x16x32_bf16(af1, bf1, acc11, 0, 0, 0);
  }

  // ---- epilogue: z [32][132] + ps [32][16] in LDS; kg=0 writes, kg=1 adds --
  __shared__ __align__(16) float zs[32 * 132 + 32 * 16];
  float* z = zs;
  float* ps = zs + 32 * 132;
  const int colb = ng * 32 + fr;
  const int rowb = fq * 4;
  if (kg == 0) {
#pragma unroll
    for (int reg = 0; reg < 4; ++reg) {
      z[(rowb + reg) * 132 + colb]           = acc00[reg];
      z[(rowb + reg) * 132 + colb + 16]      = acc01[reg];
      z[(16 + rowb + reg) * 132 + colb]      = acc10[reg];
      z[(16 + rowb + reg) * 132 + colb + 16] = acc11[reg];
    }
  }
  __syncthreads();
  if (kg == 1) {
#pragma unroll
    for (int reg = 0; reg < 4; ++reg) {
      z[(rowb + reg) * 132 + colb]           += acc00[reg];
      z[(rowb + reg) * 132 + colb + 16]      += acc01[reg];
      z[(16 + rowb + reg) * 132 + colb]      += acc10[reg];
      z[(16 + rowb + reg) * 132 + colb + 16] += acc11[reg];
    }
  }
  __syncthreads();
  {
    const int r = tid >> 4, seg = tid & 15;
    float s = 0.f;
#pragma unroll
    for (int i2 = 0; i2 < 8; ++i2) {
      const float t2 = z[r * 132 + seg * 8 + i2];
      s += t2 * t2;
    }
    ps[r * 16 + seg] = s;
  }
  __syncthreads();
  {
    const float g0 = gw[0], g1 = gw[1];
    const int r = tid >> 4, j = tid & 15;
    float s0 = 0.f, s1 = 0.f;
#pragma unroll
    for (int i2 = 0; i2 < 8; ++i2) { s0 += ps[r * 16 + i2]; s1 += ps[r * 16 + 8 + i2]; }
    const float i0 = 1.0f / fmaxf(sqrtf(s0), 1e-12f);
    const float i1 = 1.0f / fmaxf(sqrtf(s1), 1e-12f);
    float o[4];
#pragma unroll
    for (int i2 = 0; i2 < 4; ++i2) {
      const int c = j * 4 + i2;
      o[i2] = g0 * gelu_f(z[r * 132 + c] * i0) + g1 * gelu_f(z[r * 132 + 64 + c] * i1);
    }
    *reinterpret_cast<float4*>(out + (size_t)(mb + r) * 64 + j * 4) =
        make_float4(o[0], o[1], o[2], o[3]);
  }
}

// ---------------- launch ----------------
extern "C" void kernel_launch(void* const* d_in, const int* in_sizes, int n_in,
                              void* d_out, int out_size, void* d_ws, size_t ws_size,
                              hipStream_t stream) {
  (void)in_sizes; (void)n_in; (void)out_size; (void)ws_size;
  const float* x      = (const float*)d_in[0];
  const float* wg_in  = (const float*)d_in[1];
  const float* wg_lin = (const float*)d_in[2];
  const float* wg_out = (const float*)d_in[3];
  const float* we     = (const float*)d_in[4];
  float* out = (float*)d_out;
  char* ws = (char*)d_ws;

  float* upart = (float*)(ws + WS_UPART);
  int*   sel   = (int*)(ws + WS_SEL);
  float* g     = (float*)(ws + WS_G);

  k_upart   <<<dim3(2, 128), 256, 0, stream>>>(x, wg_out, upart);
  k_gate_all<<<1, 1024, 0, stream>>>(upart, wg_in, wg_lin, sel, g);
  k_moe_gemm<<<256, 512, 0, stream>>>(x, we, sel, g, out);
}